// Round 4
// baseline (336.663 us; speedup 1.0000x reference)
//
#include <hip/hip_runtime.h>
#include <math.h>

// SSIM loss. Strip design: one block = 512 threads = full 512-wide strip of
// 32 output rows. Thread t owns image column t.
//  - rolling 4-row group of (p=sigmoid(logits), g=gts) staged in LDS
//    column-major [522][4]  -> horizontal 11-tap conv via 11 ds_read_b128
//  - vertical 11-tap conv via a register ring: 5 fields x 11 pending output
//    accumulators, static mod-11 slots (fully unrolled 11-group loop)
// Each h value is produced once and scattered once: no LDS for vertical pass.
//
// R3 bug: readfirstlane(float) truncated taps to 0 -> bitcast through int.

#define KW 11
#define HALF 5
#define STRIP 32              // output rows per block
#define W 512
#define H 512
#define NT 512
#define NGRP 11               // 11 groups x 4 rows = 44 (42 used, 2 masked)
#define NIN (STRIP + 2*HALF)  // 42
#define SCOLS (W + 2*HALF)    // 522 staged columns

static constexpr float kC1 = 0.0001f;   // 0.01^2
static constexpr float kC2 = 0.0009f;   // 0.03^2

__global__ __launch_bounds__(NT, 4) void ssim_strip(
    const float* __restrict__ logits,
    const float* __restrict__ gts,
    const float* __restrict__ window,
    float* __restrict__ partial)
{
    __shared__ float sp[SCOLS][4];
    __shared__ float sg[SCOLS][4];
    __shared__ float red[NT / 64];

    const int x = threadIdx.x;

    // 1D taps = row sums of the 2D window (sum(g)=1); hoist to SGPRs.
    // NOTE: readfirstlane is int-typed -> bitcast, else float->int truncation
    // zeroes the taps (R3 failure).
    float w[KW];
#pragma unroll
    for (int k = 0; k < KW; ++k) {
        float s = 0.f;
#pragma unroll
        for (int j = 0; j < KW; ++j) s += window[k * KW + j];
        w[k] = __int_as_float(__builtin_amdgcn_readfirstlane(__float_as_int(s)));
    }

    const int img = blockIdx.x >> 4;       // 16 strips per image
    const int ty  = blockIdx.x & 15;
    const int y0  = ty * STRIP;
    const float* __restrict__ L = logits + (size_t)img * (H * W);
    const float* __restrict__ G = gts    + (size_t)img * (H * W);

    // zero the 10 halo columns once (never rewritten)
    if (x < 2 * HALF) {
        const int sc = (x < HALF) ? x : (W + x);  // 0..4, 517..521
#pragma unroll
        for (int r = 0; r < 4; ++r) { sp[sc][r] = 0.f; sg[sc][r] = 0.f; }
    }

    // register ring: pending output-row accumulators
    float r1[11], r2[11], rA[11], rB[11], rC[11];
#pragma unroll
    for (int i = 0; i < 11; ++i) { r1[i]=0.f; r2[i]=0.f; rA[i]=0.f; rB[i]=0.f; rC[i]=0.f; }

    // prefetch group 0 (input rows y0-5 .. y0-2)
    float pl[4], pgv[4];
#pragma unroll
    for (int j = 0; j < 4; ++j) {
        const int row = y0 - HALF + j;
        const bool v = (row >= 0) && (row < H);
        pl[j]  = v ? L[(size_t)row * W + x] : 0.f;
        pgv[j] = v ? G[(size_t)row * W + x] : 0.f;
    }

    float acc = 0.f;

#pragma unroll
    for (int g = 0; g < NGRP; ++g) {
        // ---- stage group g (sigmoid on valid rows; zeros outside image) ----
        float stp[4], stg[4];
#pragma unroll
        for (int j = 0; j < 4; ++j) {
            const int row = y0 - HALF + 4 * g + j;
            const bool v = (row >= 0) && (row < H);
            stp[j] = v ? 1.f / (1.f + __expf(-pl[j])) : 0.f;
            stg[j] = v ? pgv[j] : 0.f;
        }
        *(float4*)(&sp[x + HALF][0]) = make_float4(stp[0], stp[1], stp[2], stp[3]);
        *(float4*)(&sg[x + HALF][0]) = make_float4(stg[0], stg[1], stg[2], stg[3]);
        __syncthreads();

        // ---- prefetch group g+1 (hidden under compute) ----
        if (g + 1 < NGRP) {
#pragma unroll
            for (int j = 0; j < 4; ++j) {
                const int rr_next = 4 * (g + 1) + j;
                if (rr_next < NIN) {   // static: skip the 2 masked rows
                    const int row = y0 - HALF + rr_next;
                    const bool v = (row >= 0) && (row < H);
                    pl[j]  = v ? L[(size_t)row * W + x] : 0.f;
                    pgv[j] = v ? G[(size_t)row * W + x] : 0.f;
                }
            }
        }

        // ---- horizontal conv: 4 rows at once, 11 b128 reads per field ----
        float h1[4] = {0,0,0,0}, h2[4] = {0,0,0,0};
        float hA[4] = {0,0,0,0}, hB[4] = {0,0,0,0}, hC[4] = {0,0,0,0};
#pragma unroll
        for (int k = 0; k < KW; ++k) {
            const float4 pq = *(const float4*)(&sp[x + k][0]);
            const float4 gq = *(const float4*)(&sg[x + k][0]);
            const float wk = w[k];
            const float pa[4] = {pq.x, pq.y, pq.z, pq.w};
            const float ga[4] = {gq.x, gq.y, gq.z, gq.w};
#pragma unroll
            for (int c = 0; c < 4; ++c) {
                h1[c] += wk * pa[c];
                h2[c] += wk * ga[c];
                hA[c] += wk * pa[c] * pa[c];
                hB[c] += wk * ga[c] * ga[c];
                hC[c] += wk * pa[c] * ga[c];
            }
        }

        // ---- scatter into ring + finalize completed outputs ----
#pragma unroll
        for (int j = 0; j < 4; ++j) {
            const int rr = 4 * g + j;      // input-row index within strip
            if (rr < NIN) {
                const float v1 = h1[j], v2 = h2[j];
                const float vA = hA[j], vB = hB[j], vC = hC[j];
#pragma unroll
                for (int d = 0; d < KW; ++d) {
                    const int oo = rr - 2 * HALF + d;   // target output row
                    if (oo >= 0 && oo < STRIP) {        // static pruning
                        const int s = oo % 11;          // static slot
                        const float wk = w[rr - oo];
                        r1[s] += wk * v1; r2[s] += wk * v2;
                        rA[s] += wk * vA; rB[s] += wk * vB; rC[s] += wk * vC;
                    }
                }
                const int of = rr - 2 * HALF;           // output row completed
                if (of >= 0) {                          // of <= 31 since rr < 42
                    const int s = of % 11;
                    const float m1 = r1[s], m2 = r2[s];
                    const float mu11 = m1 * m1, mu22 = m2 * m2, mu12 = m1 * m2;
                    const float s11 = rA[s] - mu11;
                    const float s22 = rB[s] - mu22;
                    const float s12 = rC[s] - mu12;
                    const float num = (2.f * mu12 + kC1) * (2.f * s12 + kC2);
                    const float den = (mu11 + mu22 + kC1) * (s11 + s22 + kC2);
#if defined(__has_builtin)
#if __has_builtin(__builtin_amdgcn_rcpf)
                    acc += num * __builtin_amdgcn_rcpf(den);
#else
                    acc += num / den;
#endif
#else
                    acc += num / den;
#endif
                    r1[s] = 0.f; r2[s] = 0.f; rA[s] = 0.f; rB[s] = 0.f; rC[s] = 0.f;
                }
            }
        }
        __syncthreads();   // protect staged buffer before next group's writes
    }

    // ---- block reduction ----
#pragma unroll
    for (int off = 32; off > 0; off >>= 1) acc += __shfl_xor(acc, off);
    if ((x & 63) == 0) red[x >> 6] = acc;
    __syncthreads();
    if (x == 0) {
        float s = 0.f;
#pragma unroll
        for (int i = 0; i < NT / 64; ++i) s += red[i];
        partial[blockIdx.x] = s;
    }
}

__global__ __launch_bounds__(256) void ssim_finalize(
    const float* __restrict__ partial, int nparts, double inv_count,
    float* __restrict__ out)
{
    __shared__ double sd[256];
    const int tid = threadIdx.x;
    double s = 0.0;
    for (int i = tid; i < nparts; i += 256) s += (double)partial[i];
    sd[tid] = s;
    __syncthreads();
    for (int st = 128; st > 0; st >>= 1) {
        if (tid < st) sd[tid] += sd[tid + st];
        __syncthreads();
    }
    if (tid == 0) out[0] = (float)(1.0 - sd[0] * inv_count);
}

extern "C" void kernel_launch(void* const* d_in, const int* in_sizes, int n_in,
                              void* d_out, int out_size, void* d_ws, size_t ws_size,
                              hipStream_t stream) {
    const float* logits = (const float*)d_in[0];
    const float* gts    = (const float*)d_in[1];
    const float* window = (const float*)d_in[2];
    float* out = (float*)d_out;

    const int nimg = in_sizes[0] / (H * W);          // 32
    const int nblocks = nimg * (H / STRIP);          // 512

    float* partial = (float*)d_ws;

    ssim_strip<<<nblocks, NT, 0, stream>>>(logits, gts, window, partial);

    const double inv_count = 1.0 / ((double)nimg * H * W);
    ssim_finalize<<<1, 256, 0, stream>>>(partial, nblocks, inv_count, out);
}

// Round 5
// 154.778 us; speedup vs baseline: 2.1751x; 2.1751x over previous
//
#include <hip/hip_runtime.h>
#include <math.h>

// SSIM loss. Strip design: one block = 512 threads = full 512-wide strip of
// 32 output rows. Thread t owns image column t.
//  - rolling 4-row group of (p=sigmoid(logits), g=gts) staged in LDS
//    column-major [522][4]  -> horizontal 11-tap conv via ds_read_b128
//  - vertical 11-tap conv via a SHIFT WINDOW: 14 pending output slots x 5
//    fields in registers. All slot indices are compile-time constants even
//    with the group loop rolled (R4's mod-11 ring spilled to scratch:
//    WRITE_SIZE 588 MB, VALUBusy 13%).
// Slot p in group g = output row oo = 4g-10+p. Input row rr=4g+j contributes
// to p=j+d (d=0..10) with weight w[10-d]  (w[rr-oo], rr-oo = 10-d).
// After scattering rows j=0..3, slots 0..3 are complete -> emit, shift by 4.

#define KW 11
#define HALF 5
#define STRIP 32              // output rows per block
#define W 512
#define H 512
#define NT 512
#define NGRP 11               // 11 groups x 4 rows = 44 (rows 42,43 masked)
#define NIN (STRIP + 2*HALF)  // 42
#define SCOLS (W + 2*HALF)    // 522 staged columns
#define NSLOT 14

static constexpr float kC1 = 0.0001f;   // 0.01^2
static constexpr float kC2 = 0.0009f;   // 0.03^2

__global__ __launch_bounds__(NT, 4) void ssim_strip(
    const float* __restrict__ logits,
    const float* __restrict__ gts,
    const float* __restrict__ window,
    float* __restrict__ partial)
{
    __shared__ float sp[SCOLS][4];
    __shared__ float sg[SCOLS][4];
    __shared__ float red[NT / 64];

    const int x = threadIdx.x;

    // 1D taps = row sums of 2D window (sum(g)=1); SGPR-hoist via bitcast
    // (readfirstlane is int-typed; R3 bug was float->int truncation).
    float w[KW];
#pragma unroll
    for (int k = 0; k < KW; ++k) {
        float s = 0.f;
#pragma unroll
        for (int j = 0; j < KW; ++j) s += window[k * KW + j];
        w[k] = __int_as_float(__builtin_amdgcn_readfirstlane(__float_as_int(s)));
    }

    const int img = blockIdx.x >> 4;       // 16 strips per image
    const int ty  = blockIdx.x & 15;
    const int y0  = ty * STRIP;
    const float* __restrict__ L = logits + (size_t)img * (H * W);
    const float* __restrict__ G = gts    + (size_t)img * (H * W);

    // zero the 10 halo columns once (never rewritten)
    if (x < 2 * HALF) {
        const int sc = (x < HALF) ? x : (W + x);  // 0..4, 517..521
#pragma unroll
        for (int r = 0; r < 4; ++r) { sp[sc][r] = 0.f; sg[sc][r] = 0.f; }
    }

    // pending output-row accumulators (static indices only!)
    float P1[NSLOT], P2[NSLOT], PA[NSLOT], PB[NSLOT], PC[NSLOT];
#pragma unroll
    for (int i = 0; i < NSLOT; ++i) {
        P1[i] = 0.f; P2[i] = 0.f; PA[i] = 0.f; PB[i] = 0.f; PC[i] = 0.f;
    }

    // prefetch group 0 (input rows y0-5 .. y0-2)
    float pl[4], pgv[4];
#pragma unroll
    for (int j = 0; j < 4; ++j) {
        const int row = y0 - HALF + j;
        const bool v = (row >= 0) && (row < H);
        pl[j]  = v ? L[(size_t)row * W + x] : 0.f;
        pgv[j] = v ? G[(size_t)row * W + x] : 0.f;
    }

    float acc = 0.f;

    for (int g = 0; g < NGRP; ++g) {
        // ---- stage group g (sigmoid on valid rows; zeros outside) ----
        float stp[4], stg[4];
#pragma unroll
        for (int j = 0; j < 4; ++j) {
            const int rr = 4 * g + j;
            const int row = y0 - HALF + rr;
            const bool v = (rr < NIN) && (row >= 0) && (row < H);
            stp[j] = v ? 1.f / (1.f + __expf(-pl[j])) : 0.f;
            stg[j] = v ? pgv[j] : 0.f;
        }
        *(float4*)(&sp[x + HALF][0]) = make_float4(stp[0], stp[1], stp[2], stp[3]);
        *(float4*)(&sg[x + HALF][0]) = make_float4(stg[0], stg[1], stg[2], stg[3]);
        __syncthreads();

        // ---- prefetch group g+1 (hidden under compute) ----
        if (g + 1 < NGRP) {
#pragma unroll
            for (int j = 0; j < 4; ++j) {
                const int rr = 4 * (g + 1) + j;
                const int row = y0 - HALF + rr;
                const bool v = (rr < NIN) && (row >= 0) && (row < H);
                pl[j]  = v ? L[(size_t)row * W + x] : 0.f;
                pgv[j] = v ? G[(size_t)row * W + x] : 0.f;
            }
        }

        // ---- horizontal conv: 4 rows at once, conflict-free b128 reads ----
        float h1[4] = {0,0,0,0}, h2[4] = {0,0,0,0};
        float hA[4] = {0,0,0,0}, hB[4] = {0,0,0,0}, hC[4] = {0,0,0,0};
#pragma unroll
        for (int k = 0; k < KW; ++k) {
            const float4 pq = *(const float4*)(&sp[x + k][0]);
            const float4 gq = *(const float4*)(&sg[x + k][0]);
            const float wk = w[k];
            const float pa[4] = {pq.x, pq.y, pq.z, pq.w};
            const float ga[4] = {gq.x, gq.y, gq.z, gq.w};
#pragma unroll
            for (int c = 0; c < 4; ++c) {
                h1[c] += wk * pa[c];
                h2[c] += wk * ga[c];
                hA[c] += wk * pa[c] * pa[c];
                hB[c] += wk * ga[c] * ga[c];
                hC[c] += wk * pa[c] * ga[c];
            }
        }

        // ---- scatter rows into pending slots (all indices static) ----
#pragma unroll
        for (int j = 0; j < 4; ++j) {
#pragma unroll
            for (int d = 0; d <= 10; ++d) {
                const int p = j + d;          // slot, static
                const float wk = w[10 - d];
                P1[p] += wk * h1[j];
                P2[p] += wk * h2[j];
                PA[p] += wk * hA[j];
                PB[p] += wk * hB[j];
                PC[p] += wk * hC[j];
            }
        }

        // ---- emit completed slots 0..3 (oo = 4g-10+p), then shift by 4 ----
        const int oo0 = 4 * g - 10;
#pragma unroll
        for (int p = 0; p < 4; ++p) {
            const int oo = oo0 + p;           // uniform scalar bound check
            if (oo >= 0 && oo < STRIP) {
                const float m1 = P1[p], m2 = P2[p];
                const float mu11 = m1 * m1, mu22 = m2 * m2, mu12 = m1 * m2;
                const float s11 = PA[p] - mu11;
                const float s22 = PB[p] - mu22;
                const float s12 = PC[p] - mu12;
                const float num = (2.f * mu12 + kC1) * (2.f * s12 + kC2);
                const float den = (mu11 + mu22 + kC1) * (s11 + s22 + kC2);
                acc += num * __builtin_amdgcn_rcpf(den);
            }
        }
#pragma unroll
        for (int i = 0; i < NSLOT - 4; ++i) {
            P1[i] = P1[i + 4]; P2[i] = P2[i + 4];
            PA[i] = PA[i + 4]; PB[i] = PB[i + 4]; PC[i] = PC[i + 4];
        }
#pragma unroll
        for (int i = NSLOT - 4; i < NSLOT; ++i) {
            P1[i] = 0.f; P2[i] = 0.f; PA[i] = 0.f; PB[i] = 0.f; PC[i] = 0.f;
        }

        __syncthreads();   // protect staged buffer before next group's writes
    }

    // ---- block reduction ----
#pragma unroll
    for (int off = 32; off > 0; off >>= 1) acc += __shfl_xor(acc, off);
    if ((x & 63) == 0) red[x >> 6] = acc;
    __syncthreads();
    if (x == 0) {
        float s = 0.f;
#pragma unroll
        for (int i = 0; i < NT / 64; ++i) s += red[i];
        partial[blockIdx.x] = s;
    }
}

__global__ __launch_bounds__(256) void ssim_finalize(
    const float* __restrict__ partial, int nparts, double inv_count,
    float* __restrict__ out)
{
    __shared__ double sd[256];
    const int tid = threadIdx.x;
    double s = 0.0;
    for (int i = tid; i < nparts; i += 256) s += (double)partial[i];
    sd[tid] = s;
    __syncthreads();
    for (int st = 128; st > 0; st >>= 1) {
        if (tid < st) sd[tid] += sd[tid + st];
        __syncthreads();
    }
    if (tid == 0) out[0] = (float)(1.0 - sd[0] * inv_count);
}

extern "C" void kernel_launch(void* const* d_in, const int* in_sizes, int n_in,
                              void* d_out, int out_size, void* d_ws, size_t ws_size,
                              hipStream_t stream) {
    const float* logits = (const float*)d_in[0];
    const float* gts    = (const float*)d_in[1];
    const float* window = (const float*)d_in[2];
    float* out = (float*)d_out;

    const int nimg = in_sizes[0] / (H * W);          // 32
    const int nblocks = nimg * (H / STRIP);          // 512

    float* partial = (float*)d_ws;

    ssim_strip<<<nblocks, NT, 0, stream>>>(logits, gts, window, partial);

    const double inv_count = 1.0 / ((double)nimg * H * W);
    ssim_finalize<<<1, 256, 0, stream>>>(partial, nblocks, inv_count, out);
}

// Round 6
// 71.668 us; speedup vs baseline: 4.6975x; 2.1596x over previous
//
#include <hip/hip_runtime.h>
#include <math.h>

// SSIM loss. Strip design: one block = 512 threads = full 512-wide strip of
// 32 output rows. Thread t owns image column t.
//  - rolling 4-row group of (p=sigmoid(logits), g=gts) staged in LDS
//    column-major [522][4]  -> horizontal 11-tap conv via ds_read_b128
//  - vertical 11-tap conv via a SHIFT WINDOW: 14 pending output slots x 5
//    fields in registers, static indices.
// R5 lesson: live state (~135 VGPR) exceeded the launch_bounds(512,4) cap of
// 128 -> full spill cascade (WRITE_SIZE 459 MB, VGPR=64). Fix: (512,2) gives
// a 256-VGPR budget, and field-by-field hconv+scatter trims peak pressure.

#define KW 11
#define HALF 5
#define STRIP 32              // output rows per block
#define W 512
#define H 512
#define NT 512
#define NGRP 11               // 11 groups x 4 rows = 44 (rows 42,43 masked)
#define NIN (STRIP + 2*HALF)  // 42
#define SCOLS (W + 2*HALF)    // 522 staged columns
#define NSLOT 14

static constexpr float kC1 = 0.0001f;   // 0.01^2
static constexpr float kC2 = 0.0009f;   // 0.03^2

__global__ __launch_bounds__(NT, 2) void ssim_strip(
    const float* __restrict__ logits,
    const float* __restrict__ gts,
    const float* __restrict__ window,
    float* __restrict__ partial)
{
    __shared__ float sp[SCOLS][4];
    __shared__ float sg[SCOLS][4];
    __shared__ float red[NT / 64];

    const int x = threadIdx.x;

    // 1D taps = row sums of 2D window (sum(g)=1); SGPR-hoist via bitcast
    // (readfirstlane is int-typed; R3 bug was float->int truncation).
    float w[KW];
#pragma unroll
    for (int k = 0; k < KW; ++k) {
        float s = 0.f;
#pragma unroll
        for (int j = 0; j < KW; ++j) s += window[k * KW + j];
        w[k] = __int_as_float(__builtin_amdgcn_readfirstlane(__float_as_int(s)));
    }

    const int img = blockIdx.x >> 4;       // 16 strips per image
    const int ty  = blockIdx.x & 15;
    const int y0  = ty * STRIP;
    const float* __restrict__ L = logits + (size_t)img * (H * W);
    const float* __restrict__ G = gts    + (size_t)img * (H * W);

    // zero the 10 halo columns once (never rewritten)
    if (x < 2 * HALF) {
        const int sc = (x < HALF) ? x : (W + x);  // 0..4, 517..521
#pragma unroll
        for (int r = 0; r < 4; ++r) { sp[sc][r] = 0.f; sg[sc][r] = 0.f; }
    }

    // pending output-row accumulators (static indices only!)
    float P1[NSLOT], P2[NSLOT], PA[NSLOT], PB[NSLOT], PC[NSLOT];
#pragma unroll
    for (int i = 0; i < NSLOT; ++i) {
        P1[i] = 0.f; P2[i] = 0.f; PA[i] = 0.f; PB[i] = 0.f; PC[i] = 0.f;
    }

    // prefetch group 0 (input rows y0-5 .. y0-2)
    float pl[4], pgv[4];
#pragma unroll
    for (int j = 0; j < 4; ++j) {
        const int row = y0 - HALF + j;
        const bool v = (row >= 0) && (row < H);
        pl[j]  = v ? L[(size_t)row * W + x] : 0.f;
        pgv[j] = v ? G[(size_t)row * W + x] : 0.f;
    }

    float acc = 0.f;

    for (int g = 0; g < NGRP; ++g) {
        // ---- stage group g (sigmoid on valid rows; zeros outside) ----
        {
            float stp[4], stg[4];
#pragma unroll
            for (int j = 0; j < 4; ++j) {
                const int rr = 4 * g + j;
                const int row = y0 - HALF + rr;
                const bool v = (rr < NIN) && (row >= 0) && (row < H);
                stp[j] = v ? 1.f / (1.f + __expf(-pl[j])) : 0.f;
                stg[j] = v ? pgv[j] : 0.f;
            }
            *(float4*)(&sp[x + HALF][0]) = make_float4(stp[0], stp[1], stp[2], stp[3]);
            *(float4*)(&sg[x + HALF][0]) = make_float4(stg[0], stg[1], stg[2], stg[3]);
        }
        __syncthreads();

        // ---- prefetch group g+1 (hidden under compute) ----
        if (g + 1 < NGRP) {
#pragma unroll
            for (int j = 0; j < 4; ++j) {
                const int rr = 4 * (g + 1) + j;
                const int row = y0 - HALF + rr;
                const bool v = (rr < NIN) && (row >= 0) && (row < H);
                pl[j]  = v ? L[(size_t)row * W + x] : 0.f;
                pgv[j] = v ? G[(size_t)row * W + x] : 0.f;
            }
        }

        // ---- field-by-field horizontal conv + scatter into pending slots ----
        // (keeps only 4 h-values live at a time -> low register pressure)
#define HCONV_SCATTER(EXPR_P, EXPR_G, EXPR, PDST)                              \
        {                                                                      \
            float hv[4] = {0.f, 0.f, 0.f, 0.f};                                \
            _Pragma("unroll")                                                  \
            for (int k = 0; k < KW; ++k) {                                     \
                const float4 pq = *(const float4*)(&sp[x + k][0]);             \
                const float4 gq = *(const float4*)(&sg[x + k][0]);             \
                (void)pq; (void)gq;                                            \
                const float wk = w[k];                                         \
                hv[0] += wk * (EXPR((pq.x), (gq.x)));                          \
                hv[1] += wk * (EXPR((pq.y), (gq.y)));                          \
                hv[2] += wk * (EXPR((pq.z), (gq.z)));                          \
                hv[3] += wk * (EXPR((pq.w), (gq.w)));                          \
            }                                                                  \
            _Pragma("unroll")                                                  \
            for (int j = 0; j < 4; ++j) {                                      \
                _Pragma("unroll")                                              \
                for (int d = 0; d <= 10; ++d) {                                \
                    PDST[j + d] += w[10 - d] * hv[j];                          \
                }                                                              \
            }                                                                  \
        }

#define EP(p, gg) (p)
#define EG(p, gg) (gg)
#define EPP(p, gg) ((p) * (p))
#define EGG(p, gg) ((gg) * (gg))
#define EPG(p, gg) ((p) * (gg))
        HCONV_SCATTER(1, 0, EP,  P1)
        HCONV_SCATTER(0, 1, EG,  P2)
        HCONV_SCATTER(1, 0, EPP, PA)
        HCONV_SCATTER(0, 1, EGG, PB)
        HCONV_SCATTER(1, 1, EPG, PC)
#undef EP
#undef EG
#undef EPP
#undef EGG
#undef EPG
#undef HCONV_SCATTER

        // ---- emit completed slots 0..3 (oo = 4g-10+p), then shift by 4 ----
        const int oo0 = 4 * g - 10;
#pragma unroll
        for (int p = 0; p < 4; ++p) {
            const int oo = oo0 + p;           // uniform scalar bound check
            if (oo >= 0 && oo < STRIP) {
                const float m1 = P1[p], m2 = P2[p];
                const float mu11 = m1 * m1, mu22 = m2 * m2, mu12 = m1 * m2;
                const float s11 = PA[p] - mu11;
                const float s22 = PB[p] - mu22;
                const float s12 = PC[p] - mu12;
                const float num = (2.f * mu12 + kC1) * (2.f * s12 + kC2);
                const float den = (mu11 + mu22 + kC1) * (s11 + s22 + kC2);
                acc += num * __builtin_amdgcn_rcpf(den);
            }
        }
#pragma unroll
        for (int i = 0; i < NSLOT - 4; ++i) {
            P1[i] = P1[i + 4]; P2[i] = P2[i + 4];
            PA[i] = PA[i + 4]; PB[i] = PB[i + 4]; PC[i] = PC[i + 4];
        }
#pragma unroll
        for (int i = NSLOT - 4; i < NSLOT; ++i) {
            P1[i] = 0.f; P2[i] = 0.f; PA[i] = 0.f; PB[i] = 0.f; PC[i] = 0.f;
        }

        __syncthreads();   // protect staged buffer before next group's writes
    }

    // ---- block reduction ----
#pragma unroll
    for (int off = 32; off > 0; off >>= 1) acc += __shfl_xor(acc, off);
    if ((x & 63) == 0) red[x >> 6] = acc;
    __syncthreads();
    if (x == 0) {
        float s = 0.f;
#pragma unroll
        for (int i = 0; i < NT / 64; ++i) s += red[i];
        partial[blockIdx.x] = s;
    }
}

__global__ __launch_bounds__(256) void ssim_finalize(
    const float* __restrict__ partial, int nparts, double inv_count,
    float* __restrict__ out)
{
    __shared__ double sd[256];
    const int tid = threadIdx.x;
    double s = 0.0;
    for (int i = tid; i < nparts; i += 256) s += (double)partial[i];
    sd[tid] = s;
    __syncthreads();
    for (int st = 128; st > 0; st >>= 1) {
        if (tid < st) sd[tid] += sd[tid + st];
        __syncthreads();
    }
    if (tid == 0) out[0] = (float)(1.0 - sd[0] * inv_count);
}

extern "C" void kernel_launch(void* const* d_in, const int* in_sizes, int n_in,
                              void* d_out, int out_size, void* d_ws, size_t ws_size,
                              hipStream_t stream) {
    const float* logits = (const float*)d_in[0];
    const float* gts    = (const float*)d_in[1];
    const float* window = (const float*)d_in[2];
    float* out = (float*)d_out;

    const int nimg = in_sizes[0] / (H * W);          // 32
    const int nblocks = nimg * (H / STRIP);          // 512

    float* partial = (float*)d_ws;

    ssim_strip<<<nblocks, NT, 0, stream>>>(logits, gts, window, partial);

    const double inv_count = 1.0 / ((double)nimg * H * W);
    ssim_finalize<<<1, 256, 0, stream>>>(partial, nblocks, inv_count, out);
}

// Round 7
// 63.894 us; speedup vs baseline: 5.2691x; 1.1217x over previous
//
#include <hip/hip_runtime.h>
#include <math.h>

// SSIM loss. Strip design: one block = 512 threads = full 512-wide strip of
// 32 output rows. Thread t owns image column t.
//  - rolling 4-row group of (p=sigmoid(logits), g=gts) staged in LDS,
//    column-major [522][4], DOUBLE-BUFFERED -> 1 barrier/group
//  - horizontal 11-tap conv: COMBINED single pass over taps, 22 ds_read_b128
//    per group feeding all 5 field accumulators (R6's per-field macro did
//    110 reads/group -> LDS-pipe-bound at ~65 us)
//  - vertical 11-tap conv via a shift window: 14 pending output slots x 5
//    fields in registers, static indices.
// R5 lesson: launch_bounds(512,4) caps VGPR at 128 -> spill cascade. Use
// (512,2): 256-VGPR budget; live state ~120.

#define KW 11
#define HALF 5
#define STRIP 32              // output rows per block
#define W 512
#define H 512
#define NT 512
#define NGRP 11               // 11 groups x 4 rows = 44 (rows 42,43 masked)
#define NIN (STRIP + 2*HALF)  // 42
#define SCOLS (W + 2*HALF)    // 522 staged columns
#define NSLOT 14

static constexpr float kC1 = 0.0001f;   // 0.01^2
static constexpr float kC2 = 0.0009f;   // 0.03^2

__global__ __launch_bounds__(NT, 2) void ssim_strip(
    const float* __restrict__ logits,
    const float* __restrict__ gts,
    const float* __restrict__ window,
    float* __restrict__ partial)
{
    __shared__ float sp[2][SCOLS][4];
    __shared__ float sg[2][SCOLS][4];
    __shared__ float red[NT / 64];

    const int x = threadIdx.x;

    // 1D taps = row sums of 2D window (sum(g)=1); SGPR-hoist via bitcast
    // (readfirstlane is int-typed; R3 bug was float->int truncation).
    float w[KW];
#pragma unroll
    for (int k = 0; k < KW; ++k) {
        float s = 0.f;
#pragma unroll
        for (int j = 0; j < KW; ++j) s += window[k * KW + j];
        w[k] = __int_as_float(__builtin_amdgcn_readfirstlane(__float_as_int(s)));
    }

    const int img = blockIdx.x >> 4;       // 16 strips per image
    const int ty  = blockIdx.x & 15;
    const int y0  = ty * STRIP;
    const float* __restrict__ L = logits + (size_t)img * (H * W);
    const float* __restrict__ G = gts    + (size_t)img * (H * W);

    // zero the 10 halo columns once, both buffers (never rewritten)
    if (x < 2 * HALF) {
        const int sc = (x < HALF) ? x : (W + x);  // 0..4, 517..521
#pragma unroll
        for (int b = 0; b < 2; ++b)
#pragma unroll
            for (int r = 0; r < 4; ++r) { sp[b][sc][r] = 0.f; sg[b][sc][r] = 0.f; }
    }

    // pending output-row accumulators (static indices only!)
    float P1[NSLOT], P2[NSLOT], PA[NSLOT], PB[NSLOT], PC[NSLOT];
#pragma unroll
    for (int i = 0; i < NSLOT; ++i) {
        P1[i] = 0.f; P2[i] = 0.f; PA[i] = 0.f; PB[i] = 0.f; PC[i] = 0.f;
    }

    // prefetch group 0 (input rows y0-5 .. y0-2)
    float pl[4], pgv[4];
#pragma unroll
    for (int j = 0; j < 4; ++j) {
        const int row = y0 - HALF + j;
        const bool v = (row >= 0) && (row < H);
        pl[j]  = v ? L[(size_t)row * W + x] : 0.f;
        pgv[j] = v ? G[(size_t)row * W + x] : 0.f;
    }

    float acc = 0.f;

    for (int g = 0; g < NGRP; ++g) {
        const int b = g & 1;

        // ---- stage group g into buffer b (sigmoid; zeros outside) ----
        {
            float stp[4], stg[4];
#pragma unroll
            for (int j = 0; j < 4; ++j) {
                const int rr = 4 * g + j;
                const int row = y0 - HALF + rr;
                const bool v = (rr < NIN) && (row >= 0) && (row < H);
                stp[j] = v ? 1.f / (1.f + __expf(-pl[j])) : 0.f;
                stg[j] = v ? pgv[j] : 0.f;
            }
            *(float4*)(&sp[b][x + HALF][0]) = make_float4(stp[0], stp[1], stp[2], stp[3]);
            *(float4*)(&sg[b][x + HALF][0]) = make_float4(stg[0], stg[1], stg[2], stg[3]);
        }

        // ---- prefetch group g+1 (overlaps barrier + compute) ----
        if (g + 1 < NGRP) {
#pragma unroll
            for (int j = 0; j < 4; ++j) {
                const int rr = 4 * (g + 1) + j;
                const int row = y0 - HALF + rr;
                const bool v = (rr < NIN) && (row >= 0) && (row < H);
                pl[j]  = v ? L[(size_t)row * W + x] : 0.f;
                pgv[j] = v ? G[(size_t)row * W + x] : 0.f;
            }
        }

        // Single barrier per group: group g's reads of buffer b finish before
        // the g+1 barrier; buffer b is rewritten in group g+2, after it.
        __syncthreads();

        // ---- combined horizontal conv: one pass, all 5 fields ----
        float h1[4] = {0,0,0,0}, h2[4] = {0,0,0,0};
        float hA[4] = {0,0,0,0}, hB[4] = {0,0,0,0}, hC[4] = {0,0,0,0};
#pragma unroll
        for (int k = 0; k < KW; ++k) {
            const float4 pq = *(const float4*)(&sp[b][x + k][0]);
            const float4 gq = *(const float4*)(&sg[b][x + k][0]);
            const float wk = w[k];
            h1[0] += wk * pq.x;        h1[1] += wk * pq.y;
            h1[2] += wk * pq.z;        h1[3] += wk * pq.w;
            h2[0] += wk * gq.x;        h2[1] += wk * gq.y;
            h2[2] += wk * gq.z;        h2[3] += wk * gq.w;
            hA[0] += wk * pq.x * pq.x; hA[1] += wk * pq.y * pq.y;
            hA[2] += wk * pq.z * pq.z; hA[3] += wk * pq.w * pq.w;
            hB[0] += wk * gq.x * gq.x; hB[1] += wk * gq.y * gq.y;
            hB[2] += wk * gq.z * gq.z; hB[3] += wk * gq.w * gq.w;
            hC[0] += wk * pq.x * gq.x; hC[1] += wk * pq.y * gq.y;
            hC[2] += wk * pq.z * gq.z; hC[3] += wk * pq.w * gq.w;
        }

        // ---- scatter rows into pending slots (all indices static) ----
#pragma unroll
        for (int j = 0; j < 4; ++j) {
#pragma unroll
            for (int d = 0; d <= 10; ++d) {
                const int p = j + d;          // slot, static
                const float wk = w[10 - d];
                P1[p] += wk * h1[j];
                P2[p] += wk * h2[j];
                PA[p] += wk * hA[j];
                PB[p] += wk * hB[j];
                PC[p] += wk * hC[j];
            }
        }

        // ---- emit completed slots 0..3 (oo = 4g-10+p), then shift by 4 ----
        const int oo0 = 4 * g - 10;
#pragma unroll
        for (int p = 0; p < 4; ++p) {
            const int oo = oo0 + p;           // uniform scalar bound check
            if (oo >= 0 && oo < STRIP) {
                const float m1 = P1[p], m2 = P2[p];
                const float mu11 = m1 * m1, mu22 = m2 * m2, mu12 = m1 * m2;
                const float s11 = PA[p] - mu11;
                const float s22 = PB[p] - mu22;
                const float s12 = PC[p] - mu12;
                const float num = (2.f * mu12 + kC1) * (2.f * s12 + kC2);
                const float den = (mu11 + mu22 + kC1) * (s11 + s22 + kC2);
                acc += num * __builtin_amdgcn_rcpf(den);
            }
        }
#pragma unroll
        for (int i = 0; i < NSLOT - 4; ++i) {
            P1[i] = P1[i + 4]; P2[i] = P2[i + 4];
            PA[i] = PA[i + 4]; PB[i] = PB[i + 4]; PC[i] = PC[i + 4];
        }
#pragma unroll
        for (int i = NSLOT - 4; i < NSLOT; ++i) {
            P1[i] = 0.f; P2[i] = 0.f; PA[i] = 0.f; PB[i] = 0.f; PC[i] = 0.f;
        }
    }

    // ---- block reduction ----
#pragma unroll
    for (int off = 32; off > 0; off >>= 1) acc += __shfl_xor(acc, off);
    if ((x & 63) == 0) red[x >> 6] = acc;
    __syncthreads();
    if (x == 0) {
        float s = 0.f;
#pragma unroll
        for (int i = 0; i < NT / 64; ++i) s += red[i];
        partial[blockIdx.x] = s;
    }
}

__global__ __launch_bounds__(256) void ssim_finalize(
    const float* __restrict__ partial, int nparts, double inv_count,
    float* __restrict__ out)
{
    __shared__ double sd[256];
    const int tid = threadIdx.x;
    double s = 0.0;
    for (int i = tid; i < nparts; i += 256) s += (double)partial[i];
    sd[tid] = s;
    __syncthreads();
    for (int st = 128; st > 0; st >>= 1) {
        if (tid < st) sd[tid] += sd[tid + st];
        __syncthreads();
    }
    if (tid == 0) out[0] = (float)(1.0 - sd[0] * inv_count);
}

extern "C" void kernel_launch(void* const* d_in, const int* in_sizes, int n_in,
                              void* d_out, int out_size, void* d_ws, size_t ws_size,
                              hipStream_t stream) {
    const float* logits = (const float*)d_in[0];
    const float* gts    = (const float*)d_in[1];
    const float* window = (const float*)d_in[2];
    float* out = (float*)d_out;

    const int nimg = in_sizes[0] / (H * W);          // 32
    const int nblocks = nimg * (H / STRIP);          // 512

    float* partial = (float*)d_ws;

    ssim_strip<<<nblocks, NT, 0, stream>>>(logits, gts, window, partial);

    const double inv_count = 1.0 / ((double)nimg * H * W);
    ssim_finalize<<<1, 256, 0, stream>>>(partial, nblocks, inv_count, out);
}